// Round 1
// baseline (82.451 us; speedup 1.0000x reference)
//
#include <hip/hip_runtime.h>

// PolyLinear: out[i] = b + sum_j W[j] * prod_k x_aug[i, idx[j,k]]
// idx is the deterministic lex-order combinations_with_replacement enumeration
// (deg1: 32 terms @ W[0..31], deg2: 528 @ W[32..559], deg3: 5984 @ W[560..6543]),
// so we hardcode the loop structure instead of reading idx.
//
// Factorization per row:
//   acc = sum_a W1[a]*x_a
//       + sum_{a<=b} (x_a*x_b) * ( W2[a,b] + sum_{c>=b} W3[a,b,c]*x_c )
// Fully unrolled -> x[] stays in VGPRs (constant indices), W[] offsets are
// compile-time constants -> wave-uniform scalar loads (s_load), inner body is
// one v_fmac per deg-3 term.

__device__ __forceinline__ constexpr int off2(int a, int b) {
    // deg2 base 32; pairs (a<=b) lex order
    return 32 + 32 * a - (a * (a - 1)) / 2 + (b - a);
}

__device__ __forceinline__ constexpr int off3(int a, int b, int c) {
    // deg3 base 560; triples (a<=b<=c) lex order.
    // g3[a] = #triples with first index < a
    constexpr int g3[32] = {
        0,    528,  1024, 1489, 1924, 2330, 2708, 3059,
        3384, 3684, 3960, 4213, 4444, 4654, 4844, 5015,
        5168, 5304, 5424, 5529, 5620, 5698, 5764, 5819,
        5864, 5900, 5928, 5949, 5964, 5974, 5980, 5983};
    return 560 + g3[a] + 32 * (b - a) - ((b * (b - 1)) / 2 - (a * (a - 1)) / 2) + (c - b);
}

template <int A0, int A1>
__device__ __forceinline__ float eval_range(const float* __restrict__ W,
                                            const float (&x)[32]) {
    float acc = 0.0f;
#pragma unroll
    for (int a = A0; a < A1; ++a) {
        const float xa = x[a];
        acc = __builtin_fmaf(W[a], xa, acc);  // degree-1 term
#pragma unroll
        for (int b = a; b < 32; ++b) {
            const float pab = xa * x[b];
            float S = W[off2(a, b)];  // degree-2 weight as S init
#pragma unroll
            for (int c = b; c < 32; ++c) {
                S = __builtin_fmaf(W[off3(a, b, c)], x[c], S);  // degree-3 terms
            }
            acc = __builtin_fmaf(pab, S, acc);
        }
    }
    return acc;
}

// Block: 256 threads = 4 waves. Each wave handles one statically balanced
// a-range for the same 64 rows; LDS reduce across waves.
// deg3-FMA balance: {0..2}=1489, {3..6}=1570, {7..11}=1385, {12..31}=1540.
__global__ __launch_bounds__(256) void PolyLinear_40218073760341_kernel(
    const float* __restrict__ X,   // (rows, 32)
    const float* __restrict__ W,   // (6544,)
    const float* __restrict__ Bp,  // (1,)
    float* __restrict__ out)       // (rows,)
{
    const int lane = threadIdx.x & 63;
    const int wave = threadIdx.x >> 6;  // part id 0..3
    const int row  = blockIdx.x * 64 + lane;

    // Load this row's 32 features into registers (coalesced float4 per wave).
    float x[32];
    const float4* xr = (const float4*)(X + (long)row * 32);
#pragma unroll
    for (int i = 0; i < 8; ++i) {
        const float4 v = xr[i];
        x[4 * i + 0] = v.x;
        x[4 * i + 1] = v.y;
        x[4 * i + 2] = v.z;
        x[4 * i + 3] = v.w;
    }

    float acc;
    if (wave == 0)      acc = eval_range<0, 3>(W, x);
    else if (wave == 1) acc = eval_range<3, 7>(W, x);
    else if (wave == 2) acc = eval_range<7, 12>(W, x);
    else                acc = eval_range<12, 32>(W, x);

    __shared__ float partial[4][64];
    partial[wave][lane] = acc;
    __syncthreads();

    if (wave == 0) {
        const float r = partial[0][lane] + partial[1][lane] +
                        partial[2][lane] + partial[3][lane] + Bp[0];
        out[row] = r;
    }
}

extern "C" void kernel_launch(void* const* d_in, const int* in_sizes, int n_in,
                              void* d_out, int out_size, void* d_ws, size_t ws_size,
                              hipStream_t stream) {
    const float* X  = (const float*)d_in[0];  // (32768, 32) fp32
    const float* W  = (const float*)d_in[1];  // (1, 6544) fp32
    const float* Bp = (const float*)d_in[2];  // (1,) fp32
    // d_in[3] = idx — deterministic, unused.
    float* out = (float*)d_out;

    const int rows = in_sizes[0] / 32;  // 32768
    const int grid = rows / 64;         // 512 blocks of 256 threads
    PolyLinear_40218073760341_kernel<<<grid, 256, 0, stream>>>(X, W, Bp, out);
}